// Round 1
// baseline (302.119 us; speedup 1.0000x reference)
//
#include <hip/hip_runtime.h>
#include <math.h>

#define N_NODES 50000
#define IN_CH   128
#define HEADS   4
#define HID     64
#define NEDGE   800000
#define EPS     1e-6f
#define LN_EPS  1e-5f

// ---------------- kernel 0: bcos_w row inverse norms ----------------
__global__ void wnorm_kernel(const float* __restrict__ bcos_w,
                             float* __restrict__ inv_w) {
    int j = threadIdx.x;            // 64 threads
    float ss = 0.f;
#pragma unroll
    for (int k = 0; k < HID; ++k) {
        float v = bcos_w[j * HID + k];
        ss += v * v;
    }
    inv_w[j] = 1.0f / fmaxf(sqrtf(ss), 1e-12f);
}

// ---------------- kernel 1: h = x @ lin_w.T, per-head inv norms ------
__global__ __launch_bounds__(256) void h_kernel(const float* __restrict__ x,
                                                const float* __restrict__ lin_w,
                                                float* __restrict__ h,
                                                float* __restrict__ inv_hn) {
    // lin_w staged in LDS, padded leading dim to break stride-128 bank conflicts
    __shared__ float w[HID][IN_CH + 1];          // 33 KB
    for (int i = threadIdx.x; i < HID * IN_CH; i += 256)
        w[i / IN_CH][i % IN_CH] = lin_w[i];
    __syncthreads();

    int node = blockIdx.x * 4 + (threadIdx.x >> 6);   // 4 nodes / block
    int c    = threadIdx.x & 63;
    if (node >= N_NODES) return;

    const float* xr = x + (size_t)node * IN_CH;
    float acc = 0.f;
#pragma unroll 8
    for (int k = 0; k < IN_CH; ++k)
        acc += xr[k] * w[c][k];                  // xr[k] is wave-uniform -> L1 broadcast

    h[(size_t)node * HID + c] = acc;

    // per-head (16 lanes) sum of squares
    float ss = acc * acc;
    ss += __shfl_xor(ss, 1);
    ss += __shfl_xor(ss, 2);
    ss += __shfl_xor(ss, 4);
    ss += __shfl_xor(ss, 8);
    if ((c & 15) == 0)
        inv_hn[node * HEADS + (c >> 4)] = 1.0f / fmaxf(sqrtf(ss), 1e-12f);
}

// ---------------- kernel 2: per-edge cosine message + scatter-add ----
__global__ __launch_bounds__(256) void edge_kernel(const int* __restrict__ ei,
                                                   const float* __restrict__ h,
                                                   const float* __restrict__ inv_hn,
                                                   float* __restrict__ out_acc) {
    int lane = threadIdx.x & 63;
    int e = (int)(((size_t)blockIdx.x * 256 + threadIdx.x) >> 6);  // wave id = edge id
    if (e >= NEDGE) return;

    int row = ei[e];            // target
    int col = ei[NEDGE + e];    // source

    float hc = h[(size_t)col * HID + lane];
    float hr = h[(size_t)row * HID + lane];

    // per-head dot over 16 lanes
    float p = hc * hr;
    p += __shfl_xor(p, 1);
    p += __shfl_xor(p, 2);
    p += __shfl_xor(p, 4);
    p += __shfl_xor(p, 8);

    int head = lane >> 4;
    float cosv = p * inv_hn[col * HEADS + head] * inv_hn[row * HEADS + head];
    cosv = fminf(fmaxf(cosv, EPS), 1.0f);        // B_EXP=2 -> scale == cos

    atomicAdd(out_acc + (size_t)row * HID + lane, hc * cosv);
}

// ---------------- kernel 3: bcos linear + norm-scale + layernorm -----
__global__ __launch_bounds__(256) void final_kernel(const float* __restrict__ out_acc,
                                                    const float* __restrict__ bcos_w,
                                                    const float* __restrict__ inv_w_g,
                                                    const float* __restrict__ gamma,
                                                    const float* __restrict__ beta,
                                                    float* __restrict__ y) {
    __shared__ float w[HID][HID + 1];            // padded: kills stride-64 conflicts
    __shared__ float rowbuf[4][HID];
    __shared__ float inv_w[HID];

    for (int i = threadIdx.x; i < HID * HID; i += 256)
        w[i >> 6][i & 63] = bcos_w[i];
    if (threadIdx.x < HID) inv_w[threadIdx.x] = inv_w_g[threadIdx.x];

    int grp  = threadIdx.x >> 6;                 // wave id = node group
    int j    = threadIdx.x & 63;
    int node = blockIdx.x * 4 + grp;

    float o = (node < N_NODES) ? out_acc[(size_t)node * HID + j] : 0.f;
    rowbuf[grp][j] = o;
    __syncthreads();
    if (node >= N_NODES) return;

    // ||out_row|| via full-wave reduce
    float ss = o * o;
    ss += __shfl_xor(ss, 1);
    ss += __shfl_xor(ss, 2);
    ss += __shfl_xor(ss, 4);
    ss += __shfl_xor(ss, 8);
    ss += __shfl_xor(ss, 16);
    ss += __shfl_xor(ss, 32);
    float inv_no = 1.0f / fmaxf(sqrtf(ss), 1e-12f);

    // lin[j] = dot(out_row, bcos_w[j,:])
    float lin = 0.f;
#pragma unroll
    for (int k = 0; k < HID; ++k)
        lin += rowbuf[grp][k] * w[j][k];

    float c2 = lin * inv_no * inv_w[j];
    c2 = fminf(fmaxf(c2, EPS), 1.0f);
    float ob = lin * c2;                          // B_EXP=2 -> cos2**1

    // LayerNorm over the 64 lanes
    float mu = ob;
    mu += __shfl_xor(mu, 1);
    mu += __shfl_xor(mu, 2);
    mu += __shfl_xor(mu, 4);
    mu += __shfl_xor(mu, 8);
    mu += __shfl_xor(mu, 16);
    mu += __shfl_xor(mu, 32);
    mu *= (1.0f / 64.0f);

    float d = ob - mu;
    float var = d * d;
    var += __shfl_xor(var, 1);
    var += __shfl_xor(var, 2);
    var += __shfl_xor(var, 4);
    var += __shfl_xor(var, 8);
    var += __shfl_xor(var, 16);
    var += __shfl_xor(var, 32);
    var *= (1.0f / 64.0f);

    float r = rsqrtf(var + LN_EPS);
    y[(size_t)node * HID + j] = d * r * gamma[j] + beta[j];
}

// ---------------------------------------------------------------------
extern "C" void kernel_launch(void* const* d_in, const int* in_sizes, int n_in,
                              void* d_out, int out_size, void* d_ws, size_t ws_size,
                              hipStream_t stream) {
    const float* x      = (const float*)d_in[0];
    const int*   ei     = (const int*)d_in[1];
    const float* lin_w  = (const float*)d_in[2];
    const float* bcos_w = (const float*)d_in[3];
    const float* gamma  = (const float*)d_in[4];
    const float* beta   = (const float*)d_in[5];
    float*       y      = (float*)d_out;

    // workspace layout (floats)
    float* h       = (float*)d_ws;                        // N*64
    float* inv_hn  = h + (size_t)N_NODES * HID;           // N*4
    float* out_acc = inv_hn + (size_t)N_NODES * HEADS;    // N*64
    float* inv_w   = out_acc + (size_t)N_NODES * HID;     // 64

    hipMemsetAsync(out_acc, 0, (size_t)N_NODES * HID * sizeof(float), stream);

    wnorm_kernel<<<1, 64, 0, stream>>>(bcos_w, inv_w);

    h_kernel<<<(N_NODES + 3) / 4, 256, 0, stream>>>(x, lin_w, h, inv_hn);

    edge_kernel<<<(NEDGE * 64 + 255) / 256, 256, 0, stream>>>(ei, h, inv_hn, out_acc);

    final_kernel<<<(N_NODES + 3) / 4, 256, 0, stream>>>(out_acc, bcos_w, inv_w,
                                                        gamma, beta, y);
}